// Round 15
// baseline (536.914 us; speedup 1.0000x reference)
//
#include <hip/hip_runtime.h>
#include <cstdint>
#include <cstddef>

// B=1, N=768, CM=384, CP=128, H=12, SQK=SV=16, PQK=4, PV=8, NFIN=2112, NOUT=384
static constexpr float SCALAR_W = 0.14433756729740643f;  // 1/sqrt(3*16)
static constexpr float PTW_C    = 0.13608276348795434f;  // sqrt(1/(3*4*4.5))
static constexpr float RSQRT3   = 0.5773502691896258f;
static constexpr float FP16HUGE = 65504.0f;

// ws layout (floats)
static constexpr size_t OFF_P    = 0;          // 768*1152  [n][ q(192) | kv(384) | qp(144) | kvp(432) ]
static constexpr size_t OFF_R    = 884736;     // 768*9     [n][i*3+j]
static constexpr size_t OFF_QPG  = 891648;     // 768*144   [n][i*48 + h*4 + a]
static constexpr size_t OFF_KVPG = 1002240;    // 768*432   [n][i*144 + h*12 + e]
static constexpr size_t OFF_LG   = 1334016;    // 768*12*768  [n][h][m]
static constexpr size_t OFF_FIN  = 8633088;    // 768*2112
static constexpr size_t OFF_VCAT = 10255104;   // 768*480   [m][ v_s(192) | vp_g(288) ]
static constexpr size_t OFF_KST  = 10623744;   // 12*16*768 [h][k][m]
static constexpr size_t OFF_KPT  = 10771200;   // 12*12*768 [h][d][m]
static constexpr size_t WS_TOTAL = 10881792;   // floats = 43.5 MB

__global__ void k_sentinel(float* __restrict__ out, int nel, float val)
{
    const int i = blockIdx.x * 256 + threadIdx.x;
    if (i < nel) out[i] = val;
}

// ---------------------------------------------------------------------------
// All four projections in one launch. grid (2, 96, 4); z selects matrix.
// ---------------------------------------------------------------------------
__global__ __launch_bounds__(256) void k_proj_all(const float* __restrict__ A,
    const float* __restrict__ wq,  const float* __restrict__ bq,
    const float* __restrict__ wkv, const float* __restrict__ bkv,
    const float* __restrict__ wqp, const float* __restrict__ bqp,
    const float* __restrict__ wkvp,const float* __restrict__ bkvp,
    float* __restrict__ P)
{
    const int z = blockIdx.z;
    const float* Bm; const float* bias; int ncols, colbase;
    switch (z) {
        case 0: Bm = wq;   bias = bq;   ncols = 192; colbase = 0;   break;
        case 1: Bm = wkv;  bias = bkv;  ncols = 384; colbase = 192; break;
        case 2: Bm = wqp;  bias = bqp;  ncols = 144; colbase = 576; break;
        default:Bm = wkvp; bias = bkvp; ncols = 432; colbase = 720; break;
    }
    if (blockIdx.x * 256 >= ncols) return;
    __shared__ float At[8][384];
    const int t = threadIdx.x;
    const int r0 = blockIdx.y * 8;
    const float4* A4 = reinterpret_cast<const float4*>(A + (size_t)r0 * 384);
    float4* At4 = reinterpret_cast<float4*>(&At[0][0]);
#pragma unroll
    for (int i = 0; i < 3; ++i) At4[t + 256 * i] = A4[t + 256 * i];
    __syncthreads();
    const int col = blockIdx.x * 256 + t;
    if (col >= ncols) return;
    float acc[8] = {0.f,0.f,0.f,0.f,0.f,0.f,0.f,0.f};
    const float* bp = Bm + col;
#pragma unroll 4
    for (int k = 0; k < 384; ++k) {
        const float b = bp[(size_t)k * ncols];
#pragma unroll
        for (int r = 0; r < 8; ++r) acc[r] += At[r][k] * b;
    }
    const float bb = bias[col];
#pragma unroll
    for (int r = 0; r < 8; ++r)
        P[(size_t)(r0 + r) * 1152 + colbase + col] = acc[r] + bb;
}

// R[n][i][j]  (proven)
__global__ __launch_bounds__(256) void k_rmat(const float* __restrict__ quat,
    float* __restrict__ ws)
{
    const int o = blockIdx.x * 256 + threadIdx.x;
    if (o >= 768 * 9) return;
    const int n = o / 9, e = o - 9 * n;
    const float q0 = quat[n*4+0], q1 = quat[n*4+1], q2 = quat[n*4+2], q3 = quat[n*4+3];
    const float inv = 1.0f / sqrtf(q0*q0 + q1*q1 + q2*q2 + q3*q3);
    const float w = q0*inv, x = q1*inv, y = q2*inv, z = q3*inv;
    float R[9];
    R[0] = 1.f - 2.f*(y*y + z*z); R[1] = 2.f*(x*y - w*z); R[2] = 2.f*(x*z + w*y);
    R[3] = 2.f*(x*y + w*z); R[4] = 1.f - 2.f*(x*x + z*z); R[5] = 2.f*(y*z - w*x);
    R[6] = 2.f*(x*z - w*y); R[7] = 2.f*(y*z + w*x); R[8] = 1.f - 2.f*(x*x + y*y);
    ws[OFF_R + o] = R[e];
}

// qp_g / kvp_g  (proven)
__global__ __launch_bounds__(256) void k_rigid(const float* __restrict__ trans,
    float* __restrict__ ws)
{
    const int o = blockIdx.x * 256 + threadIdx.x;
    if (o >= 768 * 576) return;
    const int n = o / 576, e = o - 576 * n;
    const float* R = ws + OFF_R + (size_t)n * 9;
    if (e < 144) {
        const int i = e / 48, p = e - 48 * i;
        const float* Pn = ws + OFF_P + (size_t)n * 1152 + 576;
        ws[OFF_QPG + (size_t)n*144 + e] =
            R[i*3+0]*Pn[p] + R[i*3+1]*Pn[48+p] + R[i*3+2]*Pn[96+p] + trans[n*3+i];
    } else {
        const int e2 = e - 144;
        const int i = e2 / 144, p = e2 - 144 * i;
        const float* Pn = ws + OFF_P + (size_t)n * 1152 + 720;
        ws[OFF_KVPG + (size_t)n*432 + e2] =
            R[i*3+0]*Pn[p] + R[i*3+1]*Pn[144+p] + R[i*3+2]*Pn[288+p] + trans[n*3+i];
    }
}

// ---------------------------------------------------------------------------
// VCAT + k-side transposes, grid-concatenated (bodies identical to proven
// k_vcat / k_kt; range dispatch only).
// ---------------------------------------------------------------------------
__global__ __launch_bounds__(256) void k_vk(float* __restrict__ ws)
{
    const int o = blockIdx.x * 256 + threadIdx.x;
    if (o < 768 * 480) {
        const int m = o / 480, q = o - 480 * m;
        float v;
        if (q < 192) {
            const int h = q >> 4, d = q & 15;
            v = ws[OFF_P + (size_t)m*1152 + 192 + h*32 + 16 + d];
        } else {
            const int q2 = q - 192;
            const int i = q2 / 96, r = q2 - 96*i, h = r >> 3, c = r & 7;
            v = ws[OFF_KVPG + (size_t)m*432 + i*144 + h*12 + 4 + c];
        }
        ws[OFF_VCAT + o] = v;
    } else {
        const int o2 = o - 768 * 480;
        if (o2 >= 768 * 336) return;
        const int m = o2 / 336, q = o2 - 336 * m;
        if (q < 192) {
            const int h = q >> 4, k = q & 15;
            ws[OFF_KST + (size_t)(h*16 + k)*768 + m] =
                ws[OFF_P + (size_t)m*1152 + 192 + h*32 + k];
        } else {
            const int d2 = q - 192;
            const int h = d2 / 12, d = d2 - 12 * h;
            const int i = d >> 2, a = d & 3;
            ws[OFF_KPT + (size_t)(h*12 + d)*768 + m] =
                ws[OFF_KVPG + (size_t)m*432 + i*144 + h*12 + a];
        }
    }
}

// ---------------------------------------------------------------------------
// FUSED logits + a2d, m-tile = 256. grid (768, 3).
// Phase A math identical (quad scheme); phase B: h-loop, m = mt*256 + t.
// ---------------------------------------------------------------------------
__global__ __launch_bounds__(256) void k_lga(const float* __restrict__ in2d,
    const float* __restrict__ w2d, const float* __restrict__ b2d,
    const float* __restrict__ maskp, const float* __restrict__ pw_raw,
    float* __restrict__ ws)
{
    __shared__ float w2l[1536];
    __shared__ float a2l[12][260];
    __shared__ float qs[192], qpl[144], pwl[12], b2l[12];
    const int n = blockIdx.x, mt = blockIdx.y, t = threadIdx.x;
    if (t < 192) qs[t] = ws[OFF_P + (size_t)n*1152 + t] * SCALAR_W;
    if (t < 144) qpl[t] = ws[OFF_QPG + (size_t)n*144 + t];
    if (t < 12) {
        pwl[t] = PTW_C * logf(1.f + expf(pw_raw[t]));
        b2l[t] = b2d[t];
    }
    for (int i = t; i < 1536; i += 256) w2l[i] = w2d[i];
    const float mask_n = maskp[n];
    __syncthreads();

    const int cg = t & 3, pr = t >> 2;
#pragma unroll
    for (int half = 0; half < 4; ++half) {
        const int mm = half * 64 + pr;
        const int m = mt * 256 + mm;
        const float* p = in2d + ((size_t)n * 768 + m) * 128 + cg * 32;
        float acc[12] = {0,0,0,0,0,0,0,0,0,0,0,0};
#pragma unroll
        for (int cq = 0; cq < 8; ++cq) {
            const float4 v = *reinterpret_cast<const float4*>(p + cq * 4);
#pragma unroll
            for (int j = 0; j < 4; ++j) {
                const float x = (&v.x)[j];
                const int c = cg * 32 + cq * 4 + j;
#pragma unroll
                for (int h = 0; h < 12; ++h) acc[h] += x * w2l[c * 12 + h];
            }
        }
#pragma unroll
        for (int h = 0; h < 12; ++h) {
            acc[h] += __shfl_xor(acc[h], 1);
            acc[h] += __shfl_xor(acc[h], 2);
        }
        if (cg == 0) {
#pragma unroll
            for (int h = 0; h < 12; ++h)
                a2l[h][mm] = (acc[h] + b2l[h]) * RSQRT3;
        }
    }
    __syncthreads();

    const float* kst = ws + OFF_KST;
    const float* kpt = ws + OFF_KPT;
    const int m = mt * 256 + t;
    const float pen = FP16HUGE * (1.f - mask_n * maskp[m]);
#pragma unroll
    for (int h = 0; h < 12; ++h) {
        float sc = 0.f;
        const float* ks = kst + (size_t)(h*16)*768 + m;
#pragma unroll
        for (int k = 0; k < 16; ++k) sc += qs[h*16 + k] * ks[(size_t)k*768];
        float d2 = 0.f;
        const float* kp = kpt + (size_t)(h*12)*768 + m;
#pragma unroll
        for (int d = 0; d < 12; ++d) {
            const int ii = d >> 2, a = d & 3;
            const float dq = qpl[ii*48 + h*4 + a] - kp[(size_t)d*768];
            d2 += dq * dq;
        }
        ws[OFF_LG + ((size_t)n * 12 + h) * 768 + m] =
            sc - 0.5f * pwl[h] * d2 - pen + a2l[h][t];
    }
}

// ---------------------------------------------------------------------------
// FUSED softmax + vsp + v2d + epi + norm: one block (512 thr) per row n.
// res_2d via m-split: group g owns m in [g*192,(g+1)*192), all 12 heads;
// 4-way LDS partial reduction.
// ---------------------------------------------------------------------------
__global__ __launch_bounds__(512) void k_att(const float* __restrict__ in2d,
    const float* __restrict__ trans, float* __restrict__ ws)
{
    __shared__ float at[12][776];
    __shared__ float part[4][1536];
    __shared__ float fl[480];
    __shared__ float ptl[288];
    __shared__ float Rl[9], trl[3];
    const int n = blockIdx.x, t = threadIdx.x;
    const int wv = t >> 6, lane = t & 63;
    if (t < 9) Rl[t] = ws[OFF_R + n*9 + t];
    if (t < 3) trl[t] = trans[n*3 + t];
    {
        const float4* a4 = reinterpret_cast<const float4*>(ws + OFF_LG + (size_t)n * 9216);
        for (int i = t; i < 2304; i += 512) {
            const int row = i / 192, j = i - row * 192;
            *reinterpret_cast<float4*>(&at[row][j * 4]) = a4[i];
        }
    }
    __syncthreads();

    for (int h = wv; h < 12; h += 8) {
        float v[12];
        float mx = -3.0e38f;
#pragma unroll
        for (int i = 0; i < 12; ++i) { v[i] = at[h][lane + i*64]; mx = fmaxf(mx, v[i]); }
#pragma unroll
        for (int off = 32; off > 0; off >>= 1) mx = fmaxf(mx, __shfl_xor(mx, off));
        float s = 0.f;
#pragma unroll
        for (int i = 0; i < 12; ++i) { v[i] = expf(v[i] - mx); s += v[i]; }
#pragma unroll
        for (int off = 32; off > 0; off >>= 1) s += __shfl_xor(s, off);
        const float inv = 1.f / s;
#pragma unroll
        for (int i = 0; i < 12; ++i) at[h][lane + i*64] = v[i] * inv;
    }
    __syncthreads();

    // res_2d partials: group g = t>>7 owns m-chunk, all heads; c = t&127
    {
        const int c = t & 127, g = t >> 7;
        const float* p = in2d + (size_t)n * 768 * 128 + c;
        float acc[12] = {0,0,0,0,0,0,0,0,0,0,0,0};
        const int m0 = g * 192;
#pragma unroll 4
        for (int m = m0; m < m0 + 192; ++m) {
            const float x = p[(size_t)m * 128];
#pragma unroll
            for (int h = 0; h < 12; ++h) acc[h] += at[h][m] * x;
        }
#pragma unroll
        for (int h = 0; h < 12; ++h) part[g][h * 128 + c] = acc[h];
    }
    __syncthreads();
    {
        float* fo = ws + OFF_FIN + (size_t)n * 2112 + 576;
        for (int o = t; o < 1536; o += 512)
            fo[o] = part[0][o] + part[1][o] + part[2][o] + part[3][o];
    }

    // res_s + res_pt_g via VCAT -> fl
    if (t < 480) {
        int h;
        if (t < 192) h = t >> 4;
        else { const int r = (t - 192) % 96; h = r >> 3; }
        const float* v = ws + OFF_VCAT + t;
        const float* a = &at[h][0];
        float s = 0.f;
        for (int m = 0; m < 768; ++m) s += a[m] * v[(size_t)m * 480];
        fl[t] = s;
    }
    __syncthreads();

    float* fo = ws + OFF_FIN + (size_t)n * 2112;
    if (t < 192) fo[t] = fl[t];                    // res_s
    if (t < 288) {                                 // res_pt_l
        const int i = t / 96, p = t - 96 * i;
        float s = 0.f;
#pragma unroll
        for (int j = 0; j < 3; ++j)
            s += Rl[j*3 + i] * (fl[192 + j*96 + p] - trl[j]);
        fo[192 + t] = s;
        ptl[t] = s;
    }
    __syncthreads();
    if (t < 96) {                                  // pt_norm
        const float a = ptl[t], b = ptl[96 + t], c = ptl[192 + t];
        fo[480 + t] = sqrtf(1e-8f + a*a + b*b + c*c);
    }
}

// Final GEMM v2 (unchanged)
__global__ __launch_bounds__(256) void k_final(const float* __restrict__ wout,
    const float* __restrict__ bout, const float* __restrict__ ws,
    float* __restrict__ out)
{
    __shared__ float At[8][64];
    __shared__ float Bt[64][132];
    const float* fin = ws + OFF_FIN;
    const int r0 = blockIdx.y * 8;
    const int c0 = blockIdx.x * 128;
    const int t = threadIdx.x;
    const int c = t & 127, half = t >> 7;
    float acc[4] = {0.f, 0.f, 0.f, 0.f};
    for (int k0 = 0; k0 < 2112; k0 += 64) {
        __syncthreads();
        if (t < 128) {
            const int r = t >> 4, j = t & 15;
            *reinterpret_cast<float4*>(&At[r][j * 4]) =
                *reinterpret_cast<const float4*>(&fin[(size_t)(r0 + r) * 2112 + k0 + j * 4]);
        }
#pragma unroll
        for (int i = t; i < 2048; i += 256) {
            const int k = i >> 5, j = i & 31;
            *reinterpret_cast<float4*>(&Bt[k][j * 4]) =
                *reinterpret_cast<const float4*>(&wout[(size_t)(k0 + k) * 384 + c0 + j * 4]);
        }
        __syncthreads();
#pragma unroll
        for (int k = 0; k < 64; ++k) {
            const float b = Bt[k][c];
#pragma unroll
            for (int r = 0; r < 4; ++r) acc[r] += At[half*4 + r][k] * b;
        }
    }
#pragma unroll
    for (int r = 0; r < 4; ++r)
        out[(size_t)(r0 + half*4 + r) * 384 + c0 + c] = acc[r] + bout[c0 + c];
}

// ---------------------------------------------------------------------------
extern "C" void kernel_launch(void* const* d_in, const int* in_sizes, int n_in,
                              void* d_out, int out_size, void* d_ws, size_t ws_size,
                              hipStream_t stream)
{
    const float* in1d  = (const float*)d_in[0];
    const float* in2d  = (const float*)d_in[1];
    const float* maskp = (const float*)d_in[2];
    const float* quat  = (const float*)d_in[3];
    const float* trans = (const float*)d_in[4];
    const float* wq    = (const float*)d_in[5];
    const float* bq    = (const float*)d_in[6];
    const float* wkv   = (const float*)d_in[7];
    const float* bkv   = (const float*)d_in[8];
    const float* wqp   = (const float*)d_in[9];
    const float* bqp   = (const float*)d_in[10];
    const float* wkvp  = (const float*)d_in[11];
    const float* bkvp  = (const float*)d_in[12];
    const float* pwr   = (const float*)d_in[13];
    const float* w2d   = (const float*)d_in[14];
    const float* b2d   = (const float*)d_in[15];
    const float* wout  = (const float*)d_in[16];
    const float* bout  = (const float*)d_in[17];
    float* ws  = (float*)d_ws;
    float* out = (float*)d_out;

    if (ws_size < WS_TOTAL * sizeof(float)) {
        const float val = 1000.0f + (float)(ws_size / (1024.0 * 1024.0));
        k_sentinel<<<dim3((out_size + 255) / 256), dim3(256), 0, stream>>>(out, out_size, val);
        return;
    }

    dim3 blk(256);
    k_proj_all<<<dim3(2, 96, 4), blk, 0, stream>>>(in1d, wq, bq, wkv, bkv,
                                                   wqp, bqp, wkvp, bkvp, ws);
    k_rmat<<<dim3((768*9 + 255)/256), blk, 0, stream>>>(quat, ws);
    k_rigid<<<dim3((768*576 + 255)/256), blk, 0, stream>>>(trans, ws);
    k_vk<<<dim3((768*816 + 255)/256), blk, 0, stream>>>(ws);
    k_lga<<<dim3(768, 3), blk, 0, stream>>>(in2d, w2d, b2d, maskp, pwr, ws);
    k_att<<<dim3(768), dim3(512), 0, stream>>>(in2d, trans, ws);
    k_final<<<dim3(3, 96), blk, 0, stream>>>(wout, bout, ws, out);
}

// Round 16
// 495.237 us; speedup vs baseline: 1.0842x; 1.0842x over previous
//
#include <hip/hip_runtime.h>
#include <cstdint>
#include <cstddef>

// B=1, N=768, CM=384, CP=128, H=12, SQK=SV=16, PQK=4, PV=8, NFIN=2112, NOUT=384
static constexpr float SCALAR_W = 0.14433756729740643f;  // 1/sqrt(3*16)
static constexpr float PTW_C    = 0.13608276348795434f;  // sqrt(1/(3*4*4.5))
static constexpr float RSQRT3   = 0.5773502691896258f;
static constexpr float FP16HUGE = 65504.0f;

// ws layout (floats)
static constexpr size_t OFF_P    = 0;          // 768*1152  [n][ q(192) | kv(384) | qp(144) | kvp(432) ]
static constexpr size_t OFF_R    = 884736;     // 768*9     [n][i*3+j]
static constexpr size_t OFF_QPG  = 891648;     // 768*144   [n][i*48 + h*4 + a]
static constexpr size_t OFF_KVPG = 1002240;    // 768*432   [n][i*144 + h*12 + e]
static constexpr size_t OFF_LG   = 1334016;    // 768*12*768  [n][h][m]
static constexpr size_t OFF_FIN  = 8633088;    // 768*2112
static constexpr size_t OFF_VCAT = 10255104;   // 768*480   [m][ v_s(192) | vp_g(288) ]
static constexpr size_t OFF_KST  = 10623744;   // 12*16*768 [h][k][m]
static constexpr size_t OFF_KPT  = 10771200;   // 12*12*768 [h][d][m]
static constexpr size_t WS_TOTAL = 10881792;   // floats = 43.5 MB

__global__ void k_sentinel(float* __restrict__ out, int nel, float val)
{
    const int i = blockIdx.x * 256 + threadIdx.x;
    if (i < nel) out[i] = val;
}

// ---------------------------------------------------------------------------
// All four projections in one launch. grid (2, 96, 4); z selects matrix.
// ---------------------------------------------------------------------------
__global__ __launch_bounds__(256) void k_proj_all(const float* __restrict__ A,
    const float* __restrict__ wq,  const float* __restrict__ bq,
    const float* __restrict__ wkv, const float* __restrict__ bkv,
    const float* __restrict__ wqp, const float* __restrict__ bqp,
    const float* __restrict__ wkvp,const float* __restrict__ bkvp,
    float* __restrict__ P)
{
    const int z = blockIdx.z;
    const float* Bm; const float* bias; int ncols, colbase;
    switch (z) {
        case 0: Bm = wq;   bias = bq;   ncols = 192; colbase = 0;   break;
        case 1: Bm = wkv;  bias = bkv;  ncols = 384; colbase = 192; break;
        case 2: Bm = wqp;  bias = bqp;  ncols = 144; colbase = 576; break;
        default:Bm = wkvp; bias = bkvp; ncols = 432; colbase = 720; break;
    }
    if (blockIdx.x * 256 >= ncols) return;
    __shared__ float At[8][384];
    const int t = threadIdx.x;
    const int r0 = blockIdx.y * 8;
    const float4* A4 = reinterpret_cast<const float4*>(A + (size_t)r0 * 384);
    float4* At4 = reinterpret_cast<float4*>(&At[0][0]);
#pragma unroll
    for (int i = 0; i < 3; ++i) At4[t + 256 * i] = A4[t + 256 * i];
    __syncthreads();
    const int col = blockIdx.x * 256 + t;
    if (col >= ncols) return;
    float acc[8] = {0.f,0.f,0.f,0.f,0.f,0.f,0.f,0.f};
    const float* bp = Bm + col;
#pragma unroll 4
    for (int k = 0; k < 384; ++k) {
        const float b = bp[(size_t)k * ncols];
#pragma unroll
        for (int r = 0; r < 8; ++r) acc[r] += At[r][k] * b;
    }
    const float bb = bias[col];
#pragma unroll
    for (int r = 0; r < 8; ++r)
        P[(size_t)(r0 + r) * 1152 + colbase + col] = acc[r] + bb;
}

// R[n][i][j]  (proven)
__global__ __launch_bounds__(256) void k_rmat(const float* __restrict__ quat,
    float* __restrict__ ws)
{
    const int o = blockIdx.x * 256 + threadIdx.x;
    if (o >= 768 * 9) return;
    const int n = o / 9, e = o - 9 * n;
    const float q0 = quat[n*4+0], q1 = quat[n*4+1], q2 = quat[n*4+2], q3 = quat[n*4+3];
    const float inv = 1.0f / sqrtf(q0*q0 + q1*q1 + q2*q2 + q3*q3);
    const float w = q0*inv, x = q1*inv, y = q2*inv, z = q3*inv;
    float R[9];
    R[0] = 1.f - 2.f*(y*y + z*z); R[1] = 2.f*(x*y - w*z); R[2] = 2.f*(x*z + w*y);
    R[3] = 2.f*(x*y + w*z); R[4] = 1.f - 2.f*(x*x + z*z); R[5] = 2.f*(y*z - w*x);
    R[6] = 2.f*(x*z - w*y); R[7] = 2.f*(y*z + w*x); R[8] = 1.f - 2.f*(x*x + y*y);
    ws[OFF_R + o] = R[e];
}

// qp_g / kvp_g  (proven)
__global__ __launch_bounds__(256) void k_rigid(const float* __restrict__ trans,
    float* __restrict__ ws)
{
    const int o = blockIdx.x * 256 + threadIdx.x;
    if (o >= 768 * 576) return;
    const int n = o / 576, e = o - 576 * n;
    const float* R = ws + OFF_R + (size_t)n * 9;
    if (e < 144) {
        const int i = e / 48, p = e - 48 * i;
        const float* Pn = ws + OFF_P + (size_t)n * 1152 + 576;
        ws[OFF_QPG + (size_t)n*144 + e] =
            R[i*3+0]*Pn[p] + R[i*3+1]*Pn[48+p] + R[i*3+2]*Pn[96+p] + trans[n*3+i];
    } else {
        const int e2 = e - 144;
        const int i = e2 / 144, p = e2 - 144 * i;
        const float* Pn = ws + OFF_P + (size_t)n * 1152 + 720;
        ws[OFF_KVPG + (size_t)n*432 + e2] =
            R[i*3+0]*Pn[p] + R[i*3+1]*Pn[144+p] + R[i*3+2]*Pn[288+p] + trans[n*3+i];
    }
}

// ---------------------------------------------------------------------------
// VCAT + k-side transposes, grid-concatenated (proven)
// ---------------------------------------------------------------------------
__global__ __launch_bounds__(256) void k_vk(float* __restrict__ ws)
{
    const int o = blockIdx.x * 256 + threadIdx.x;
    if (o < 768 * 480) {
        const int m = o / 480, q = o - 480 * m;
        float v;
        if (q < 192) {
            const int h = q >> 4, d = q & 15;
            v = ws[OFF_P + (size_t)m*1152 + 192 + h*32 + 16 + d];
        } else {
            const int q2 = q - 192;
            const int i = q2 / 96, r = q2 - 96*i, h = r >> 3, c = r & 7;
            v = ws[OFF_KVPG + (size_t)m*432 + i*144 + h*12 + 4 + c];
        }
        ws[OFF_VCAT + o] = v;
    } else {
        const int o2 = o - 768 * 480;
        if (o2 >= 768 * 336) return;
        const int m = o2 / 336, q = o2 - 336 * m;
        if (q < 192) {
            const int h = q >> 4, k = q & 15;
            ws[OFF_KST + (size_t)(h*16 + k)*768 + m] =
                ws[OFF_P + (size_t)m*1152 + 192 + h*32 + k];
        } else {
            const int d2 = q - 192;
            const int h = d2 / 12, d = d2 - 12 * h;
            const int i = d >> 2, a = d & 3;
            ws[OFF_KPT + (size_t)(h*12 + d)*768 + m] =
                ws[OFF_KVPG + (size_t)m*432 + i*144 + h*12 + a];
        }
    }
}

// ---------------------------------------------------------------------------
// FUSED logits + a2d, m-tile = 256. grid (768, 3).
// Phase A: quad scheme with INTERLEAVED channel map c = cq*16 + cg*4 + j:
//  - w2l reads across cg-groups now 48 floats apart -> 2-way bank alias (free)
//  - in2d reads of the 4 cg lanes form one contiguous 64B line
// ---------------------------------------------------------------------------
__global__ __launch_bounds__(256) void k_lga(const float* __restrict__ in2d,
    const float* __restrict__ w2d, const float* __restrict__ b2d,
    const float* __restrict__ maskp, const float* __restrict__ pw_raw,
    float* __restrict__ ws)
{
    __shared__ float w2l[1536];
    __shared__ float a2l[12][260];
    __shared__ float qs[192], qpl[144], pwl[12], b2l[12];
    const int n = blockIdx.x, mt = blockIdx.y, t = threadIdx.x;
    if (t < 192) qs[t] = ws[OFF_P + (size_t)n*1152 + t] * SCALAR_W;
    if (t < 144) qpl[t] = ws[OFF_QPG + (size_t)n*144 + t];
    if (t < 12) {
        pwl[t] = PTW_C * logf(1.f + expf(pw_raw[t]));
        b2l[t] = b2d[t];
    }
    for (int i = t; i < 1536; i += 256) w2l[i] = w2d[i];
    const float mask_n = maskp[n];
    __syncthreads();

    const int cg = t & 3, pr = t >> 2;
    const int cg4 = cg * 4;
#pragma unroll
    for (int half = 0; half < 4; ++half) {
        const int mm = half * 64 + pr;
        const int m = mt * 256 + mm;
        const float* p = in2d + ((size_t)n * 768 + m) * 128;
        float acc[12] = {0,0,0,0,0,0,0,0,0,0,0,0};
#pragma unroll
        for (int cq = 0; cq < 8; ++cq) {
            const float4 v = *reinterpret_cast<const float4*>(p + cq * 16 + cg4);
#pragma unroll
            for (int j = 0; j < 4; ++j) {
                const float x = (&v.x)[j];
                const int c = cq * 16 + cg4 + j;
#pragma unroll
                for (int h = 0; h < 12; ++h) acc[h] += x * w2l[c * 12 + h];
            }
        }
#pragma unroll
        for (int h = 0; h < 12; ++h) {
            acc[h] += __shfl_xor(acc[h], 1);
            acc[h] += __shfl_xor(acc[h], 2);
        }
        if (cg == 0) {
#pragma unroll
            for (int h = 0; h < 12; ++h)
                a2l[h][mm] = (acc[h] + b2l[h]) * RSQRT3;
        }
    }
    __syncthreads();

    const float* kst = ws + OFF_KST;
    const float* kpt = ws + OFF_KPT;
    const int m = mt * 256 + t;
    const float pen = FP16HUGE * (1.f - mask_n * maskp[m]);
#pragma unroll
    for (int h = 0; h < 12; ++h) {
        float sc = 0.f;
        const float* ks = kst + (size_t)(h*16)*768 + m;
#pragma unroll
        for (int k = 0; k < 16; ++k) sc += qs[h*16 + k] * ks[(size_t)k*768];
        float d2 = 0.f;
        const float* kp = kpt + (size_t)(h*12)*768 + m;
#pragma unroll
        for (int d = 0; d < 12; ++d) {
            const int ii = d >> 2, a = d & 3;
            const float dq = qpl[ii*48 + h*4 + a] - kp[(size_t)d*768];
            d2 += dq * dq;
        }
        ws[OFF_LG + ((size_t)n * 12 + h) * 768 + m] =
            sc - 0.5f * pwl[h] * d2 - pen + a2l[h][t];
    }
}

// ---------------------------------------------------------------------------
// FUSED softmax + vsp + v2d + epi + norm  (proven, unchanged from R15)
// ---------------------------------------------------------------------------
__global__ __launch_bounds__(512) void k_att(const float* __restrict__ in2d,
    const float* __restrict__ trans, float* __restrict__ ws)
{
    __shared__ float at[12][776];
    __shared__ float part[4][1536];
    __shared__ float fl[480];
    __shared__ float ptl[288];
    __shared__ float Rl[9], trl[3];
    const int n = blockIdx.x, t = threadIdx.x;
    const int wv = t >> 6, lane = t & 63;
    if (t < 9) Rl[t] = ws[OFF_R + n*9 + t];
    if (t < 3) trl[t] = trans[n*3 + t];
    {
        const float4* a4 = reinterpret_cast<const float4*>(ws + OFF_LG + (size_t)n * 9216);
        for (int i = t; i < 2304; i += 512) {
            const int row = i / 192, j = i - row * 192;
            *reinterpret_cast<float4*>(&at[row][j * 4]) = a4[i];
        }
    }
    __syncthreads();

    for (int h = wv; h < 12; h += 8) {
        float v[12];
        float mx = -3.0e38f;
#pragma unroll
        for (int i = 0; i < 12; ++i) { v[i] = at[h][lane + i*64]; mx = fmaxf(mx, v[i]); }
#pragma unroll
        for (int off = 32; off > 0; off >>= 1) mx = fmaxf(mx, __shfl_xor(mx, off));
        float s = 0.f;
#pragma unroll
        for (int i = 0; i < 12; ++i) { v[i] = expf(v[i] - mx); s += v[i]; }
#pragma unroll
        for (int off = 32; off > 0; off >>= 1) s += __shfl_xor(s, off);
        const float inv = 1.f / s;
#pragma unroll
        for (int i = 0; i < 12; ++i) at[h][lane + i*64] = v[i] * inv;
    }
    __syncthreads();

    // res_2d partials: group g = t>>7 owns m-chunk, all heads; c = t&127
    {
        const int c = t & 127, g = t >> 7;
        const float* p = in2d + (size_t)n * 768 * 128 + c;
        float acc[12] = {0,0,0,0,0,0,0,0,0,0,0,0};
        const int m0 = g * 192;
#pragma unroll 4
        for (int m = m0; m < m0 + 192; ++m) {
            const float x = p[(size_t)m * 128];
#pragma unroll
            for (int h = 0; h < 12; ++h) acc[h] += at[h][m] * x;
        }
#pragma unroll
        for (int h = 0; h < 12; ++h) part[g][h * 128 + c] = acc[h];
    }
    __syncthreads();
    {
        float* fo = ws + OFF_FIN + (size_t)n * 2112 + 576;
        for (int o = t; o < 1536; o += 512)
            fo[o] = part[0][o] + part[1][o] + part[2][o] + part[3][o];
    }

    // res_s + res_pt_g via VCAT -> fl
    if (t < 480) {
        int h;
        if (t < 192) h = t >> 4;
        else { const int r = (t - 192) % 96; h = r >> 3; }
        const float* v = ws + OFF_VCAT + t;
        const float* a = &at[h][0];
        float s = 0.f;
        for (int m = 0; m < 768; ++m) s += a[m] * v[(size_t)m * 480];
        fl[t] = s;
    }
    __syncthreads();

    float* fo = ws + OFF_FIN + (size_t)n * 2112;
    if (t < 192) fo[t] = fl[t];                    // res_s
    if (t < 288) {                                 // res_pt_l
        const int i = t / 96, p = t - 96 * i;
        float s = 0.f;
#pragma unroll
        for (int j = 0; j < 3; ++j)
            s += Rl[j*3 + i] * (fl[192 + j*96 + p] - trl[j]);
        fo[192 + t] = s;
        ptl[t] = s;
    }
    __syncthreads();
    if (t < 96) {                                  // pt_norm
        const float a = ptl[t], b = ptl[96 + t], c = ptl[192 + t];
        fo[480 + t] = sqrtf(1e-8f + a*a + b*b + c*c);
    }
}

// Final GEMM v2 (unchanged)
__global__ __launch_bounds__(256) void k_final(const float* __restrict__ wout,
    const float* __restrict__ bout, const float* __restrict__ ws,
    float* __restrict__ out)
{
    __shared__ float At[8][64];
    __shared__ float Bt[64][132];
    const float* fin = ws + OFF_FIN;
    const int r0 = blockIdx.y * 8;
    const int c0 = blockIdx.x * 128;
    const int t = threadIdx.x;
    const int c = t & 127, half = t >> 7;
    float acc[4] = {0.f, 0.f, 0.f, 0.f};
    for (int k0 = 0; k0 < 2112; k0 += 64) {
        __syncthreads();
        if (t < 128) {
            const int r = t >> 4, j = t & 15;
            *reinterpret_cast<float4*>(&At[r][j * 4]) =
                *reinterpret_cast<const float4*>(&fin[(size_t)(r0 + r) * 2112 + k0 + j * 4]);
        }
#pragma unroll
        for (int i = t; i < 2048; i += 256) {
            const int k = i >> 5, j = i & 31;
            *reinterpret_cast<float4*>(&Bt[k][j * 4]) =
                *reinterpret_cast<const float4*>(&wout[(size_t)(k0 + k) * 384 + c0 + j * 4]);
        }
        __syncthreads();
#pragma unroll
        for (int k = 0; k < 64; ++k) {
            const float b = Bt[k][c];
#pragma unroll
            for (int r = 0; r < 4; ++r) acc[r] += At[half*4 + r][k] * b;
        }
    }
#pragma unroll
    for (int r = 0; r < 4; ++r)
        out[(size_t)(r0 + half*4 + r) * 384 + c0 + c] = acc[r] + bout[c0 + c];
}

// ---------------------------------------------------------------------------
extern "C" void kernel_launch(void* const* d_in, const int* in_sizes, int n_in,
                              void* d_out, int out_size, void* d_ws, size_t ws_size,
                              hipStream_t stream)
{
    const float* in1d  = (const float*)d_in[0];
    const float* in2d  = (const float*)d_in[1];
    const float* maskp = (const float*)d_in[2];
    const float* quat  = (const float*)d_in[3];
    const float* trans = (const float*)d_in[4];
    const float* wq    = (const float*)d_in[5];
    const float* bq    = (const float*)d_in[6];
    const float* wkv   = (const float*)d_in[7];
    const float* bkv   = (const float*)d_in[8];
    const float* wqp   = (const float*)d_in[9];
    const float* bqp   = (const float*)d_in[10];
    const float* wkvp  = (const float*)d_in[11];
    const float* bkvp  = (const float*)d_in[12];
    const float* pwr   = (const float*)d_in[13];
    const float* w2d   = (const float*)d_in[14];
    const float* b2d   = (const float*)d_in[15];
    const float* wout  = (const float*)d_in[16];
    const float* bout  = (const float*)d_in[17];
    float* ws  = (float*)d_ws;
    float* out = (float*)d_out;

    if (ws_size < WS_TOTAL * sizeof(float)) {
        const float val = 1000.0f + (float)(ws_size / (1024.0 * 1024.0));
        k_sentinel<<<dim3((out_size + 255) / 256), dim3(256), 0, stream>>>(out, out_size, val);
        return;
    }

    dim3 blk(256);
    k_proj_all<<<dim3(2, 96, 4), blk, 0, stream>>>(in1d, wq, bq, wkv, bkv,
                                                   wqp, bqp, wkvp, bkvp, ws);
    k_rmat<<<dim3((768*9 + 255)/256), blk, 0, stream>>>(quat, ws);
    k_rigid<<<dim3((768*576 + 255)/256), blk, 0, stream>>>(trans, ws);
    k_vk<<<dim3((768*816 + 255)/256), blk, 0, stream>>>(ws);
    k_lga<<<dim3(768, 3), blk, 0, stream>>>(in2d, w2d, b2d, maskp, pwr, ws);
    k_att<<<dim3(768), dim3(512), 0, stream>>>(in2d, trans, ws);
    k_final<<<dim3(3, 96), blk, 0, stream>>>(wout, bout, ws, out);
}